// Round 1
// baseline (1256.298 us; speedup 1.0000x reference)
//
#include <hip/hip_runtime.h>
#include <stdint.h>

#define EE 8
#define TT 1024
#define DD 2048
#define HH 4096

typedef unsigned short u16;
using s16x8 = __attribute__((ext_vector_type(8))) short;
using f32x4 = __attribute__((ext_vector_type(4))) float;

#define AS1 __attribute__((address_space(1)))
#define AS3 __attribute__((address_space(3)))

__device__ __forceinline__ uint32_t pack_bf16(float lo, float hi) {
#if __has_builtin(__builtin_amdgcn_cvt_pk_bf16_f32)
  typedef __bf16 bf16x2 __attribute__((ext_vector_type(2)));
  bf16x2 r = __builtin_amdgcn_cvt_pk_bf16_f32(lo, hi);
  return __builtin_bit_cast(uint32_t, r);
#else
  uint32_t ulo = __builtin_bit_cast(uint32_t, lo);
  uint32_t uhi = __builtin_bit_cast(uint32_t, hi);
  ulo += 0x7fffu + ((ulo >> 16) & 1u);
  uhi += 0x7fffu + ((uhi >> 16) & 1u);
  return (ulo >> 16) | (uhi & 0xffff0000u);
#endif
}

__device__ __forceinline__ u16 bf16_bits(float v) {
  uint32_t u = __builtin_bit_cast(uint32_t, v);
  u += 0x7fffu + ((u >> 16) & 1u);
  return (u16)(u >> 16);
}

// ---------------------------------------------------------------------------
// Kernel 1: h[e,t,h] = silu(x@w1) * (x@w3^T), h stored bf16 in workspace.
// BM=BN=128, BK=32. x-tile shared by both GEMMs. w1 [D,H] transposed in
// staging; all LDS tiles stored [row][k] with row stride 40 (pad) so
// ds_read_b128 fragments are conflict-free.
// ---------------------------------------------------------------------------
__global__ __launch_bounds__(256, 2)
void k1_upgate(const float* __restrict__ x, const float* __restrict__ w1,
               const float* __restrict__ w3, u16* __restrict__ hout) {
  const int e  = blockIdx.z;
  const int t0 = blockIdx.y * 128;
  const int h0 = blockIdx.x * 128;
  const int tid = threadIdx.x;
  const int lane = tid & 63;
  const int wave = tid >> 6;
  const int wm = (wave >> 1) * 64;
  const int wn = (wave & 1) * 64;
  const int l15 = lane & 15;
  const int quad = lane >> 4;

  __shared__ u16 sX [128 * 40];
  __shared__ u16 sW1[128 * 40];
  __shared__ u16 sW3[128 * 40];

  // staging maps
  const int sr = tid >> 3;   // 0..31  (x / w3 row; 4 passes of 32 rows)
  const int sc = tid & 7;    // float4 column within BK=32
  const int k2 = tid >> 4;   // 0..15  (w1 k-pair)
  const int ns = tid & 15;   // 0..15  (w1 n-segment)

  const float* xg  = x  + (size_t)(e * TT + t0 + sr) * DD + sc * 4;
  const float* w3g = w3 + (size_t)e * HH * DD + (size_t)(h0 + sr) * DD + sc * 4;
  const float* w1g = w1 + (size_t)e * DD * HH + (size_t)(2 * k2) * HH + h0 + ns * 4;

  f32x4 acc1[4][4], acc3[4][4];
  #pragma unroll
  for (int i = 0; i < 4; ++i)
    #pragma unroll
    for (int j = 0; j < 4; ++j) { acc1[i][j] = (f32x4)0.f; acc3[i][j] = (f32x4)0.f; }

  float4 rx[4], rw[4], r0[2], r1[2];

  auto load_tiles = [&](int ko) {
    #pragma unroll
    for (int p = 0; p < 4; ++p) {
      rx[p] = *(const float4*)(xg  + (size_t)p * 32 * DD + (size_t)ko * 32);
      rw[p] = *(const float4*)(w3g + (size_t)p * 32 * DD + (size_t)ko * 32);
    }
    #pragma unroll
    for (int j = 0; j < 2; ++j) {
      r0[j] = *(const float4*)(w1g + (size_t)ko * 32 * HH + j * 64);
      r1[j] = *(const float4*)(w1g + (size_t)ko * 32 * HH + HH + j * 64);
    }
  };

  load_tiles(0);

  for (int ko = 0; ko < DD / 32; ++ko) {
    __syncthreads();
    // x & w3: [row][k] direct
    #pragma unroll
    for (int p = 0; p < 4; ++p) {
      int row = sr + p * 32;
      uint2 vx; vx.x = pack_bf16(rx[p].x, rx[p].y); vx.y = pack_bf16(rx[p].z, rx[p].w);
      uint2 vw; vw.x = pack_bf16(rw[p].x, rw[p].y); vw.y = pack_bf16(rw[p].z, rw[p].w);
      *(uint2*)&sX [row * 40 + sc * 4] = vx;
      *(uint2*)&sW3[row * 40 + sc * 4] = vw;
    }
    // w1: transpose [k][n] -> [n][k], packing k-pairs into b32 writes
    #pragma unroll
    for (int j = 0; j < 2; ++j) {
      int nb = ns * 4 + j * 64;
      *(uint32_t*)&sW1[(nb + 0) * 40 + 2 * k2] = pack_bf16(r0[j].x, r1[j].x);
      *(uint32_t*)&sW1[(nb + 1) * 40 + 2 * k2] = pack_bf16(r0[j].y, r1[j].y);
      *(uint32_t*)&sW1[(nb + 2) * 40 + 2 * k2] = pack_bf16(r0[j].z, r1[j].z);
      *(uint32_t*)&sW1[(nb + 3) * 40 + 2 * k2] = pack_bf16(r0[j].w, r1[j].w);
    }
    __syncthreads();
    if (ko + 1 < DD / 32) load_tiles(ko + 1);  // prefetch overlaps MFMA below

    s16x8 af[4];
    #pragma unroll
    for (int im = 0; im < 4; ++im)
      af[im] = *(const s16x8*)&sX[(wm + im * 16 + l15) * 40 + quad * 8];
    #pragma unroll
    for (int jn = 0; jn < 4; ++jn) {
      s16x8 b1 = *(const s16x8*)&sW1[(wn + jn * 16 + l15) * 40 + quad * 8];
      s16x8 b3 = *(const s16x8*)&sW3[(wn + jn * 16 + l15) * 40 + quad * 8];
      #pragma unroll
      for (int im = 0; im < 4; ++im) {
        acc1[im][jn] = __builtin_amdgcn_mfma_f32_16x16x32_bf16(af[im], b1, acc1[im][jn], 0, 0, 0);
        acc3[im][jn] = __builtin_amdgcn_mfma_f32_16x16x32_bf16(af[im], b3, acc3[im][jn], 0, 0, 0);
      }
    }
  }

  // epilogue: h = silu(acc1) * acc3 -> bf16  (C layout: col=lane&15, row=quad*4+r)
  #pragma unroll
  for (int im = 0; im < 4; ++im) {
    #pragma unroll
    for (int jn = 0; jn < 4; ++jn) {
      #pragma unroll
      for (int r = 0; r < 4; ++r) {
        int row = wm + im * 16 + quad * 4 + r;
        int col = wn + jn * 16 + l15;
        float a = acc1[im][jn][r];
        float g = acc3[im][jn][r];
        float s = 1.0f / (1.0f + __expf(-a));
        hout[(size_t)(e * TT + t0 + row) * HH + h0 + col] = bf16_bits(a * s * g);
      }
    }
  }
}

// ---------------------------------------------------------------------------
// Kernel 2: out[e,t,d] = h @ w2^T.  A (h, bf16) staged via global_load_lds
// width-16 into unpadded [128][32]; B (w2 fp32) staged via registers with
// pad-40 rows.
// ---------------------------------------------------------------------------
__global__ __launch_bounds__(256, 3)
void k2_down(const u16* __restrict__ hin, const float* __restrict__ w2,
             float* __restrict__ out) {
  const int e  = blockIdx.z;
  const int t0 = blockIdx.y * 128;
  const int d0 = blockIdx.x * 128;
  const int tid = threadIdx.x;
  const int lane = tid & 63;
  const int wave = tid >> 6;
  const int wm = (wave >> 1) * 64;
  const int wn = (wave & 1) * 64;
  const int l15 = lane & 15;
  const int quad = lane >> 4;

  __shared__ u16 sA[128 * 32];   // unpadded: global_load_lds lane-contiguous
  __shared__ u16 sB[128 * 40];

  const int sr = tid >> 3;
  const int sc = tid & 7;

  const u16*   hg  = hin + (size_t)(e * TT + t0) * HH;
  const float* w2g = w2  + (size_t)e * DD * HH + (size_t)(d0 + sr) * HH + sc * 4;

  const int am = wave * 32 + (lane >> 2);   // + i*16
  const int ak = (lane & 3) * 8;

  f32x4 acc[4][4];
  #pragma unroll
  for (int i = 0; i < 4; ++i)
    #pragma unroll
    for (int j = 0; j < 4; ++j) acc[i][j] = (f32x4)0.f;

  float4 rb[4];
  auto load_b = [&](int ko) {
    #pragma unroll
    for (int p = 0; p < 4; ++p)
      rb[p] = *(const float4*)(w2g + (size_t)p * 32 * HH + (size_t)ko * 32);
  };

  load_b(0);

  for (int ko = 0; ko < HH / 32; ++ko) {
    __syncthreads();
    // A tile: async direct-to-LDS, 2 x 1KB per wave, wave-uniform LDS base
    #pragma unroll
    for (int i = 0; i < 2; ++i) {
      const u16* gp = hg + (size_t)(am + i * 16) * HH + ko * 32 + ak;
      __builtin_amdgcn_global_load_lds((AS1 uint32_t*)gp,
                                       (AS3 uint32_t*)&sA[wave * 1024 + i * 512],
                                       16, 0, 0);
    }
    // B tile: fp32 -> bf16, [n][k] pad-40
    #pragma unroll
    for (int p = 0; p < 4; ++p) {
      int row = sr + p * 32;
      uint2 vb; vb.x = pack_bf16(rb[p].x, rb[p].y); vb.y = pack_bf16(rb[p].z, rb[p].w);
      *(uint2*)&sB[row * 40 + sc * 4] = vb;
    }
    __syncthreads();   // drains vmcnt -> glds data visible
    if (ko + 1 < HH / 32) load_b(ko + 1);

    s16x8 af[4];
    #pragma unroll
    for (int im = 0; im < 4; ++im)
      af[im] = *(const s16x8*)&sA[(wm + im * 16 + l15) * 32 + quad * 8];
    #pragma unroll
    for (int jn = 0; jn < 4; ++jn) {
      s16x8 bf = *(const s16x8*)&sB[(wn + jn * 16 + l15) * 40 + quad * 8];
      #pragma unroll
      for (int im = 0; im < 4; ++im)
        acc[im][jn] = __builtin_amdgcn_mfma_f32_16x16x32_bf16(af[im], bf, acc[im][jn], 0, 0, 0);
    }
  }

  #pragma unroll
  for (int im = 0; im < 4; ++im) {
    #pragma unroll
    for (int jn = 0; jn < 4; ++jn) {
      #pragma unroll
      for (int r = 0; r < 4; ++r) {
        int row = wm + im * 16 + quad * 4 + r;
        int col = wn + jn * 16 + l15;
        out[(size_t)(e * TT + t0 + row) * DD + d0 + col] = acc[im][jn][r];
      }
    }
  }
}

extern "C" void kernel_launch(void* const* d_in, const int* in_sizes, int n_in,
                              void* d_out, int out_size, void* d_ws, size_t ws_size,
                              hipStream_t stream) {
  const float* x  = (const float*)d_in[0];
  const float* w1 = (const float*)d_in[1];
  const float* w2 = (const float*)d_in[2];
  const float* w3 = (const float*)d_in[3];
  float* out = (float*)d_out;
  u16* hbuf = (u16*)d_ws;   // E*T*H bf16 = 67 MB scratch

  dim3 g1(HH / 128, TT / 128, EE);
  k1_upgate<<<g1, dim3(256), 0, stream>>>(x, w1, w3, hbuf);

  dim3 g2(DD / 128, TT / 128, EE);
  k2_down<<<g2, dim3(256), 0, stream>>>(hbuf, w2, out);
}